// Round 1
// baseline (767.690 us; speedup 1.0000x reference)
//
#include <hip/hip_runtime.h>
#include <math.h>

// Problem constants
#define kB   8
#define kCin 64
#define kCout 128
#define kH   192
#define kW   384
#define kHo  96
#define kWo  192
#define kE   128
#define kK   32
#define kOut6N (kB * kCout * kHo * kWo)  // 18,874,368

// ---------------------------------------------------------------------------
// Kernel 1: gates. One block per (batch, gate). 128 threads.
// logits = emb @ W + b; top-32; softmax; scatter. Also emits compact lists.
// ---------------------------------------------------------------------------
__global__ void moe_gates_kernel(const float* __restrict__ emb,
                                 const float* __restrict__ gw1, const float* __restrict__ gb1,
                                 const float* __restrict__ gw2, const float* __restrict__ gb2,
                                 float* __restrict__ g_out,      // [2][8][128] at d_out tail
                                 int* __restrict__ act_idx,      // [2][8][32]
                                 float* __restrict__ act_gate) { // [2][8][32]
  const int b = blockIdx.x;
  const int g = blockIdx.y;
  const int c = threadIdx.x;  // 0..127
  const float* __restrict__ w = g ? gw2 : gw1;
  const float* __restrict__ bias = g ? gb2 : gb1;

  __shared__ float sl[128];
  __shared__ float sv[128];
  __shared__ int si[128];
  __shared__ float sel_val[kK];
  __shared__ int sel_idx[kK];
  __shared__ int taken[128];
  __shared__ float gate_full[128];
  __shared__ float ssum;

  float acc = bias[c];
  for (int e = 0; e < kE; ++e) acc += emb[b * kE + e] * w[e * kCout + c];
  sl[c] = acc;
  taken[c] = 0;
  gate_full[c] = 0.f;
  __syncthreads();

  // iterative argmax top-32 (tie: lowest index first, matches lax.top_k)
  for (int i = 0; i < kK; ++i) {
    sv[c] = taken[c] ? -__builtin_inff() : sl[c];
    si[c] = c;
    __syncthreads();
    for (int s = 64; s > 0; s >>= 1) {
      if (c < s) {
        if (sv[c + s] > sv[c] || (sv[c + s] == sv[c] && si[c + s] < si[c])) {
          sv[c] = sv[c + s];
          si[c] = si[c + s];
        }
      }
      __syncthreads();
    }
    if (c == 0) {
      sel_val[i] = sv[0];
      sel_idx[i] = si[0];
      taken[si[0]] = 1;
    }
    __syncthreads();
  }
  if (c == 0) {
    float m = sel_val[0], s = 0.f;
    for (int i = 0; i < kK; ++i) s += expf(sel_val[i] - m);
    ssum = s;
  }
  __syncthreads();
  if (c < kK) {
    float gv = expf(sel_val[c] - sel_val[0]) / ssum;
    act_idx[(g * kB + b) * kK + c] = sel_idx[c];
    act_gate[(g * kB + b) * kK + c] = gv;
    gate_full[sel_idx[c]] = gv;
  }
  __syncthreads();
  g_out[(g * kB + b) * kCout + c] = gate_full[c];
}

// ---------------------------------------------------------------------------
// Kernel 2: gather compact weights.
//  w1c[b][ci][r][j]  = conv1_w[act1[b][j]][ci][r]            (8*64*9*32)
//  w2c[b][i][r][j]   = conv2_w[act2[b][j]][act1[b][i]][r]    (8*32*9*32)
//  dswT[ci][c]       = ds_w[c][ci] * gamma[c] / sqrt(1+eps)  (64*128)
// ---------------------------------------------------------------------------
__global__ void moe_gather_kernel(const float* __restrict__ w1, const float* __restrict__ w2,
                                  const float* __restrict__ dsw, const float* __restrict__ gamma,
                                  const int* __restrict__ act_idx,
                                  float* __restrict__ w1c, float* __restrict__ w2c,
                                  float* __restrict__ dswT) {
  int idx = blockIdx.x * 256 + threadIdx.x;
  const int N1 = kB * kCin * 9 * kK;  // 147456
  const int N2 = kB * kK * 9 * kK;    // 73728
  const int N3 = kCin * kCout;        // 8192
  if (idx < N1) {
    int j = idx & 31;
    int t = idx >> 5;
    int r = t % 9;
    t /= 9;
    int ci = t % kCin;
    int b = t / kCin;
    int c = act_idx[b * kK + j];
    w1c[idx] = w1[(c * kCin + ci) * 9 + r];
  } else if ((idx -= N1) < N2) {
    int j = idx & 31;
    int t = idx >> 5;
    int r = t % 9;
    t /= 9;
    int i = t % kK;
    int b = t / kK;
    int co = act_idx[256 + b * kK + j];
    int cin = act_idx[b * kK + i];
    w2c[idx] = w2[(co * kCout + cin) * 9 + r];
  } else if ((idx -= N2) < N3) {
    int c = idx & 127;
    int ci = idx >> 7;
    dswT[idx] = dsw[c * kCin + ci] * gamma[c] / sqrtf(1.f + 1e-5f);
  }
}

// ---------------------------------------------------------------------------
// Kernel 3: conv1 (3x3, stride 2, pad 1), only 32 active output channels,
// * gate, leaky -> out2c [b][j][y][x] compact.
// Block = (b, y): 256 threads, thread = 8 channels (per wave) x 3 px.
// Weights via wave-uniform scalar loads; x staged in LDS (16-ci chunks).
// ---------------------------------------------------------------------------
__global__ __launch_bounds__(256) void moe_conv1_kernel(
    const float* __restrict__ x, const float* __restrict__ w1c,
    const float* __restrict__ act_gate, float* __restrict__ out2c) {
  const int y = blockIdx.x;
  const int b = blockIdx.y;
  const int tid = threadIdx.x;
  const int tx = tid & 63;
  const int ty = __builtin_amdgcn_readfirstlane(tid >> 6);

  __shared__ float xs[16][3][388];

  float acc[8][3];
#pragma unroll
  for (int c = 0; c < 8; ++c)
#pragma unroll
    for (int p = 0; p < 3; ++p) acc[c][p] = 0.f;

  for (int cb = 0; cb < kCin; cb += 16) {
    __syncthreads();
    for (int e = tid; e < 16 * 3 * 388; e += 256) {
      int col = e % 388;
      int t = e / 388;
      int r = t % 3;
      int ci = t / 3;
      int gcol = col - 1;
      int grow = 2 * y - 1 + r;
      float v = 0.f;
      if (gcol >= 0 && gcol < kW && grow >= 0)
        v = x[((size_t)((b * kCin + cb + ci) * kH + grow)) * kW + gcol];
      xs[ci][r][col] = v;
    }
    __syncthreads();
    for (int ci = 0; ci < 16; ++ci) {
      float xr[3][8];
#pragma unroll
      for (int r = 0; r < 3; ++r)
#pragma unroll
        for (int q = 0; q < 8; ++q) xr[r][q] = xs[ci][r][6 * tx + q];
      const float* __restrict__ wp = w1c + (size_t)((b * kCin + cb + ci) * 9) * 32 + ty * 8;
#pragma unroll
      for (int ky = 0; ky < 3; ++ky)
#pragma unroll
        for (int kx = 0; kx < 3; ++kx) {
          float wv[8];
#pragma unroll
          for (int q = 0; q < 8; ++q) wv[q] = wp[(ky * 3 + kx) * 32 + q];
#pragma unroll
          for (int c = 0; c < 8; ++c)
#pragma unroll
            for (int p = 0; p < 3; ++p) acc[c][p] += xr[ky][2 * p + kx] * wv[c];
        }
    }
  }
#pragma unroll
  for (int c = 0; c < 8; ++c) {
    int j = ty * 8 + c;
    float gv = act_gate[b * kK + j];
#pragma unroll
    for (int p = 0; p < 3; ++p) {
      float v = acc[c][p] * gv;
      v = v > 0.f ? v : 0.2f * v;
      out2c[((size_t)(b * kK + j) * kHo + y) * kWo + 3 * tx + p] = v;
    }
  }
}

// ---------------------------------------------------------------------------
// Kernel 4: conv2 (3x3, stride 1, pad 1) on compact 32-ch input, 32 active
// output channels, * gate, leaky -> out4c compact.
// ---------------------------------------------------------------------------
__global__ __launch_bounds__(256) void moe_conv2_kernel(
    const float* __restrict__ out2c, const float* __restrict__ w2c,
    const float* __restrict__ act_gate2, float* __restrict__ out4c) {
  const int y = blockIdx.x;
  const int b = blockIdx.y;
  const int tid = threadIdx.x;
  const int tx = tid & 63;
  const int ty = __builtin_amdgcn_readfirstlane(tid >> 6);

  __shared__ float s2[32][3][196];

  for (int e = tid; e < 32 * 3 * 196; e += 256) {
    int col = e % 196;
    int t = e / 196;
    int r = t % 3;
    int ci = t / 3;
    int gcol = col - 1;
    int grow = y - 1 + r;
    float v = 0.f;
    if (gcol >= 0 && gcol < kWo && grow >= 0 && grow < kHo)
      v = out2c[((size_t)(b * kK + ci) * kHo + grow) * kWo + gcol];
    s2[ci][r][col] = v;
  }
  __syncthreads();

  float acc[8][3];
#pragma unroll
  for (int c = 0; c < 8; ++c)
#pragma unroll
    for (int p = 0; p < 3; ++p) acc[c][p] = 0.f;

  for (int ci = 0; ci < 32; ++ci) {
    float xr[3][5];
#pragma unroll
    for (int r = 0; r < 3; ++r)
#pragma unroll
      for (int q = 0; q < 5; ++q) xr[r][q] = s2[ci][r][3 * tx + q];
    const float* __restrict__ wp = w2c + (size_t)((b * kK + ci) * 9) * 32 + ty * 8;
#pragma unroll
    for (int ky = 0; ky < 3; ++ky)
#pragma unroll
      for (int kx = 0; kx < 3; ++kx) {
        float wv[8];
#pragma unroll
        for (int q = 0; q < 8; ++q) wv[q] = wp[(ky * 3 + kx) * 32 + q];
#pragma unroll
        for (int c = 0; c < 8; ++c)
#pragma unroll
          for (int p = 0; p < 3; ++p) acc[c][p] += xr[ky][p + kx] * wv[c];
      }
  }
#pragma unroll
  for (int c = 0; c < 8; ++c) {
    int j = ty * 8 + c;
    float gv = act_gate2[b * kK + j];
#pragma unroll
    for (int p = 0; p < 3; ++p) {
      float v = acc[c][p] * gv;
      v = v > 0.f ? v : 0.2f * v;
      out4c[((size_t)(b * kK + j) * kHo + y) * kWo + 3 * tx + p] = v;
    }
  }
}

// ---------------------------------------------------------------------------
// Kernel 5: fused downsample 1x1 s2 conv + BN + scatter-add out4 + leaky.
// out6[b,c,y,x] = leaky( dsT·x + beta + (c active in g2 ? out4c : 0) )
// ---------------------------------------------------------------------------
__global__ __launch_bounds__(256) void moe_final_kernel(
    const float* __restrict__ x, const float* __restrict__ dswT,
    const float* __restrict__ beta, const int* __restrict__ act_idx2,
    const float* __restrict__ out4c, float* __restrict__ out6) {
  const int y = blockIdx.x;
  const int b = blockIdx.y;
  const int tid = threadIdx.x;
  const int tx = tid & 63;
  const int ty = __builtin_amdgcn_readfirstlane(tid >> 6);

  __shared__ float xs[64][192];
  __shared__ float o4[32][192];
  __shared__ int inv2[128];

  for (int e = tid; e < 64 * 192; e += 256) {
    int col = e % 192;
    int ci = e / 192;
    xs[ci][col] = x[((size_t)((b * kCin + ci) * kH + 2 * y)) * kW + 2 * col];
  }
  for (int e = tid; e < 32 * 192; e += 256) {
    int col = e % 192;
    int s = e / 192;
    o4[s][col] = out4c[((size_t)(b * kK + s) * kHo + y) * kWo + col];
  }
  if (tid < 128) inv2[tid] = -1;
  __syncthreads();
  if (tid < 32) inv2[act_idx2[b * kK + tid]] = tid;
  __syncthreads();

  for (int cblk = 0; cblk < 4; ++cblk) {
    float acc[8][3];
#pragma unroll
    for (int c = 0; c < 8; ++c)
#pragma unroll
      for (int p = 0; p < 3; ++p) acc[c][p] = 0.f;

    for (int ci = 0; ci < 64; ++ci) {
      float xv[3];
#pragma unroll
      for (int p = 0; p < 3; ++p) xv[p] = xs[ci][3 * tx + p];
      const float* __restrict__ wp = dswT + ci * 128 + ty * 32 + cblk * 8;
      float wv[8];
#pragma unroll
      for (int q = 0; q < 8; ++q) wv[q] = wp[q];
#pragma unroll
      for (int c = 0; c < 8; ++c)
#pragma unroll
        for (int p = 0; p < 3; ++p) acc[c][p] += xv[p] * wv[c];
    }
#pragma unroll
    for (int c = 0; c < 8; ++c) {
      int ch = ty * 32 + cblk * 8 + c;
      float bt = beta[ch];
      int s = inv2[ch];
#pragma unroll
      for (int p = 0; p < 3; ++p) {
        float v = acc[c][p] + bt;
        if (s >= 0) v += o4[s][3 * tx + p];
        v = v > 0.f ? v : 0.2f * v;
        out6[((size_t)(b * kCout + ch) * kHo + y) * kWo + 3 * tx + p] = v;
      }
    }
  }
}

// ---------------------------------------------------------------------------
extern "C" void kernel_launch(void* const* d_in, const int* in_sizes, int n_in,
                              void* d_out, int out_size, void* d_ws, size_t ws_size,
                              hipStream_t stream) {
  (void)in_sizes; (void)n_in; (void)out_size; (void)ws_size;
  const float* x   = (const float*)d_in[0];
  const float* emb = (const float*)d_in[1];
  const float* w1  = (const float*)d_in[2];
  const float* w2  = (const float*)d_in[3];
  const float* dsw = (const float*)d_in[4];
  const float* dsg = (const float*)d_in[5];
  const float* dsb = (const float*)d_in[6];
  const float* gw1 = (const float*)d_in[7];
  const float* gb1 = (const float*)d_in[8];
  const float* gw2 = (const float*)d_in[9];
  const float* gb2 = (const float*)d_in[10];

  float* out6  = (float*)d_out;
  float* g_out = out6 + kOut6N;  // g1 [8][128] then g2 [8][128]

  // ws layout (4-byte units):
  //   [0,512)        act_idx  (int)  [2][8][32]
  //   [512,1024)     act_gate (f32)  [2][8][32]
  //   [1024,148480)  w1c   8*64*9*32
  //   [148480,222208) w2c  8*32*9*32
  //   [222208,230400) dswT 64*128
  //   [230400,4948992) out2c 8*32*96*192
  //   [4948992,9667584) out4c 8*32*96*192       (total ~38.7 MB)
  float* wsf      = (float*)d_ws;
  int* act_idx    = (int*)d_ws;
  float* act_gate = wsf + 512;
  float* w1c      = wsf + 1024;
  float* w2c      = wsf + 148480;
  float* dswT     = wsf + 222208;
  float* out2c    = wsf + 230400;
  float* out4c    = wsf + 4948992;

  moe_gates_kernel<<<dim3(kB, 2), 128, 0, stream>>>(emb, gw1, gb1, gw2, gb2,
                                                    g_out, act_idx, act_gate);
  moe_gather_kernel<<<dim3(896), 256, 0, stream>>>(w1, w2, dsw, dsg, act_idx,
                                                   w1c, w2c, dswT);
  moe_conv1_kernel<<<dim3(kHo, kB), 256, 0, stream>>>(x, w1c, act_gate, out2c);
  moe_conv2_kernel<<<dim3(kHo, kB), 256, 0, stream>>>(out2c, w2c, act_gate + 256, out4c);
  moe_final_kernel<<<dim3(kHo, kB), 256, 0, stream>>>(x, dswT, dsb, act_idx + 256,
                                                      out4c, out6);
}

// Round 6
// 471.521 us; speedup vs baseline: 1.6281x; 1.6281x over previous
//
#include <hip/hip_runtime.h>
#include <math.h>

// Problem constants
#define kB   8
#define kCin 64
#define kCout 128
#define kH   192
#define kW   384
#define kHo  96
#define kWo  192
#define kE   128
#define kK   32
#define kOut6N (kB * kCout * kHo * kWo)  // 18,874,368

// ---------------------------------------------------------------------------
// Kernel 1: gates. One block per (batch, gate). 64 threads = 1 wave.
// logits = emb @ W + b; iterative shuffle-based top-32; softmax; scatter.
// ---------------------------------------------------------------------------
__global__ void moe_gates_kernel(const float* __restrict__ emb,
                                 const float* __restrict__ gw1, const float* __restrict__ gb1,
                                 const float* __restrict__ gw2, const float* __restrict__ gb2,
                                 float* __restrict__ g_out,      // [2][8][128] at d_out tail
                                 int* __restrict__ act_idx,      // [2][8][32]
                                 float* __restrict__ act_gate) { // [2][8][32]
  const int b = blockIdx.x;
  const int g = blockIdx.y;
  const int lane = threadIdx.x;  // 0..63
  const float* __restrict__ w = g ? gw2 : gw1;
  const float* __restrict__ bias = g ? gb2 : gb1;

  float l0 = bias[lane];
  float l1 = bias[lane + 64];
  for (int e = 0; e < kE; ++e) {
    float ev = emb[b * kE + e];
    l0 += ev * w[e * kCout + lane];
    l1 += ev * w[e * kCout + lane + 64];
  }

  float selv = 0.f;
  int seli = 0;
  const float NEG = -__builtin_inff();
  for (int i = 0; i < kK; ++i) {
    float v;
    int idx;
    if (l1 > l0) { v = l1; idx = lane + 64; } else { v = l0; idx = lane; }
    // butterfly argmax across 64 lanes, tie -> lowest index (matches lax.top_k)
    for (int m = 1; m < 64; m <<= 1) {
      float ov = __shfl_xor(v, m);
      int oi = __shfl_xor(idx, m);
      if (ov > v || (ov == v && oi < idx)) { v = ov; idx = oi; }
    }
    if (lane == i) { selv = v; seli = idx; }
    if (idx == lane) l0 = NEG;
    else if (idx == lane + 64) l1 = NEG;
  }
  float m0 = __shfl(selv, 0);
  float ev = (lane < kK) ? expf(selv - m0) : 0.f;
  float s = ev;
  for (int m = 1; m < 64; m <<= 1) s += __shfl_xor(s, m);
  float gv = ev / s;

  __shared__ float gf[128];
  gf[lane] = 0.f;
  gf[lane + 64] = 0.f;
  __syncthreads();
  if (lane < kK) {
    act_idx[(g * kB + b) * kK + lane] = seli;
    act_gate[(g * kB + b) * kK + lane] = gv;
    gf[seli] = gv;
  }
  __syncthreads();
  g_out[(g * kB + b) * kCout + lane] = gf[lane];
  g_out[(g * kB + b) * kCout + lane + 64] = gf[lane + 64];
}

// ---------------------------------------------------------------------------
// Kernel 2: gather compact weights.
// ---------------------------------------------------------------------------
__global__ void moe_gather_kernel(const float* __restrict__ w1, const float* __restrict__ w2,
                                  const float* __restrict__ dsw, const float* __restrict__ gamma,
                                  const int* __restrict__ act_idx,
                                  float* __restrict__ w1c, float* __restrict__ w2c,
                                  float* __restrict__ dswT) {
  int idx = blockIdx.x * 256 + threadIdx.x;
  const int N1 = kB * kCin * 9 * kK;  // 147456
  const int N2 = kB * kK * 9 * kK;    // 73728
  const int N3 = kCin * kCout;        // 8192
  if (idx < N1) {
    int j = idx & 31;
    int t = idx >> 5;
    int r = t % 9;
    t /= 9;
    int ci = t % kCin;
    int b = t / kCin;
    int c = act_idx[b * kK + j];
    w1c[idx] = w1[(c * kCin + ci) * 9 + r];
  } else if ((idx -= N1) < N2) {
    int j = idx & 31;
    int t = idx >> 5;
    int r = t % 9;
    t /= 9;
    int i = t % kK;
    int b = t / kK;
    int co = act_idx[256 + b * kK + j];
    int cin = act_idx[b * kK + i];
    w2c[idx] = w2[(co * kCout + cin) * 9 + r];
  } else if ((idx -= N2) < N3) {
    int c = idx & 127;
    int ci = idx >> 7;
    dswT[idx] = dsw[c * kCin + ci] * gamma[c] / sqrtf(1.f + 1e-5f);
  }
}

// ---------------------------------------------------------------------------
// Kernel 3: conv1 (3x3 s2 p1), 32 active out-channels, *gate, leaky.
// Block (y,b), 512 threads = 8 waves. Wave ty: 4 out-ch; lane: 3 px (tx+64p).
// LDS: ci-chunk of 8, left-padded by 4 cols for aligned float4 staging.
// ---------------------------------------------------------------------------
__global__ __launch_bounds__(512, 6) void moe_conv1_kernel(
    const float* __restrict__ x, const float* __restrict__ w1c,
    const float* __restrict__ act_gate, float* __restrict__ out2c) {
  const int y = blockIdx.x;
  const int b = blockIdx.y;
  const int tid = threadIdx.x;
  const int tx = tid & 63;
  const int ty = __builtin_amdgcn_readfirstlane(tid >> 6);  // 0..7

  __shared__ __align__(16) float xs[8][3][392];  // col c <-> global col c-4

  float acc[4][3];
#pragma unroll
  for (int c = 0; c < 4; ++c)
#pragma unroll
    for (int p = 0; p < 3; ++p) acc[c][p] = 0.f;

  for (int cb = 0; cb < kCin; cb += 8) {
    __syncthreads();
    // stage: 8ci*3r*96 float4 interior + 48 float4 zero edges
    for (int v = tid; v < 2304 + 48; v += 512) {
      if (v < 2304) {
        int col4 = v % 96;
        int t = v / 96;
        int r = t % 3;
        int ci = t / 3;
        int grow = 2 * y - 1 + r;
        float4 val = make_float4(0.f, 0.f, 0.f, 0.f);
        if (grow >= 0)
          val = *(const float4*)&x[((size_t)((b * kCin + cb + ci) * kH + grow)) * kW + 4 * col4];
        *(float4*)&xs[ci][r][4 + 4 * col4] = val;
      } else {
        int e = v - 2304;  // 0..47
        int side = e & 1;
        int t = e >> 1;
        int r = t % 3;
        int ci = t / 3;
        *(float4*)&xs[ci][r][side ? 388 : 0] = make_float4(0.f, 0.f, 0.f, 0.f);
      }
    }
    __syncthreads();
#pragma unroll 2
    for (int ci = 0; ci < 8; ++ci) {
      float xr[3][3][3];  // [p][ky][kx]
#pragma unroll
      for (int p = 0; p < 3; ++p)
#pragma unroll
        for (int r = 0; r < 3; ++r)
#pragma unroll
          for (int kx = 0; kx < 3; ++kx)
            xr[p][r][kx] = xs[ci][r][2 * tx + 128 * p + kx + 3];
      const float* __restrict__ wp = w1c + (size_t)((b * kCin + cb + ci) * 9) * 32 + ty * 4;
#pragma unroll
      for (int ky = 0; ky < 3; ++ky)
#pragma unroll
        for (int kx = 0; kx < 3; ++kx) {
          float wv[4];
#pragma unroll
          for (int q = 0; q < 4; ++q) wv[q] = wp[(ky * 3 + kx) * 32 + q];
#pragma unroll
          for (int c = 0; c < 4; ++c)
#pragma unroll
            for (int p = 0; p < 3; ++p) acc[c][p] += xr[p][ky][kx] * wv[c];
        }
    }
  }
#pragma unroll
  for (int c = 0; c < 4; ++c) {
    int j = ty * 4 + c;
    float gv = act_gate[b * kK + j];
#pragma unroll
    for (int p = 0; p < 3; ++p) {
      float v = acc[c][p] * gv;
      v = v > 0.f ? v : 0.2f * v;
      out2c[((size_t)(b * kK + j) * kHo + y) * kWo + tx + 64 * p] = v;
    }
  }
}

// ---------------------------------------------------------------------------
// Kernel 4: conv2 (3x3 s1 p1) on compact 32-ch input -> 32 active out-ch.
// Same structure as conv1.
// ---------------------------------------------------------------------------
__global__ __launch_bounds__(512, 6) void moe_conv2_kernel(
    const float* __restrict__ out2c, const float* __restrict__ w2c,
    const float* __restrict__ act_gate2, float* __restrict__ out4c) {
  const int y = blockIdx.x;
  const int b = blockIdx.y;
  const int tid = threadIdx.x;
  const int tx = tid & 63;
  const int ty = __builtin_amdgcn_readfirstlane(tid >> 6);

  __shared__ __align__(16) float s2[8][3][200];  // col c <-> global col c-4

  float acc[4][3];
#pragma unroll
  for (int c = 0; c < 4; ++c)
#pragma unroll
    for (int p = 0; p < 3; ++p) acc[c][p] = 0.f;

  for (int cb = 0; cb < kK; cb += 8) {
    __syncthreads();
    // stage: 8ci*3r*48 float4 interior + 48 float4 zero edges
    for (int v = tid; v < 1152 + 48; v += 512) {
      if (v < 1152) {
        int col4 = v % 48;
        int t = v / 48;
        int r = t % 3;
        int ci = t / 3;
        int grow = y - 1 + r;
        float4 val = make_float4(0.f, 0.f, 0.f, 0.f);
        if (grow >= 0 && grow < kHo)
          val = *(const float4*)&out2c[((size_t)(b * kK + cb + ci) * kHo + grow) * kWo + 4 * col4];
        *(float4*)&s2[ci][r][4 + 4 * col4] = val;
      } else {
        int e = v - 1152;
        int side = e & 1;
        int t = e >> 1;
        int r = t % 3;
        int ci = t / 3;
        *(float4*)&s2[ci][r][side ? 196 : 0] = make_float4(0.f, 0.f, 0.f, 0.f);
      }
    }
    __syncthreads();
#pragma unroll 2
    for (int ci = 0; ci < 8; ++ci) {
      float xr[3][3][3];  // [p][ky][kx]
#pragma unroll
      for (int p = 0; p < 3; ++p)
#pragma unroll
        for (int r = 0; r < 3; ++r)
#pragma unroll
          for (int kx = 0; kx < 3; ++kx)
            xr[p][r][kx] = s2[ci][r][tx + 64 * p + kx + 3];
      const float* __restrict__ wp = w2c + (size_t)((b * kK + cb + ci) * 9) * 32 + ty * 4;
#pragma unroll
      for (int ky = 0; ky < 3; ++ky)
#pragma unroll
        for (int kx = 0; kx < 3; ++kx) {
          float wv[4];
#pragma unroll
          for (int q = 0; q < 4; ++q) wv[q] = wp[(ky * 3 + kx) * 32 + q];
#pragma unroll
          for (int c = 0; c < 4; ++c)
#pragma unroll
            for (int p = 0; p < 3; ++p) acc[c][p] += xr[p][ky][kx] * wv[c];
        }
    }
  }
#pragma unroll
  for (int c = 0; c < 4; ++c) {
    int j = ty * 4 + c;
    float gv = act_gate2[b * kK + j];
#pragma unroll
    for (int p = 0; p < 3; ++p) {
      float v = acc[c][p] * gv;
      v = v > 0.f ? v : 0.2f * v;
      out4c[((size_t)(b * kK + j) * kHo + y) * kWo + tx + 64 * p] = v;
    }
  }
}

// ---------------------------------------------------------------------------
// Kernel 5: fused downsample 1x1 s2 conv + BN + scatter-add out4 + leaky.
// Block (y,b), 512 threads; wave ty: 16 dense out-ch; lane: 3 px.
// ---------------------------------------------------------------------------
__global__ __launch_bounds__(512, 5) void moe_final_kernel(
    const float* __restrict__ x, const float* __restrict__ dswT,
    const float* __restrict__ beta, const int* __restrict__ act_idx2,
    const float* __restrict__ out4c, float* __restrict__ out6) {
  const int y = blockIdx.x;
  const int b = blockIdx.y;
  const int tid = threadIdx.x;
  const int tx = tid & 63;
  const int ty = __builtin_amdgcn_readfirstlane(tid >> 6);

  __shared__ __align__(16) float xs[16][192];
  __shared__ __align__(16) float o4[32][192];
  __shared__ int inv2[128];

  // stage o4 (float4), init inv2
  for (int v = tid; v < 1536; v += 512) {
    int col4 = v % 48;
    int s = v / 48;
    *(float4*)&o4[s][4 * col4] =
        *(const float4*)&out4c[((size_t)(b * kK + s) * kHo + y) * kWo + 4 * col4];
  }
  if (tid < 128) inv2[tid] = -1;
  __syncthreads();
  if (tid < kK) inv2[act_idx2[b * kK + tid]] = tid;

  float acc[16][3];
#pragma unroll
  for (int q = 0; q < 16; ++q)
#pragma unroll
    for (int p = 0; p < 3; ++p) acc[q][p] = 0.f;

  for (int cb = 0; cb < kCin; cb += 16) {
    __syncthreads();
    for (int v = tid; v < 16 * 192; v += 512) {
      int col = v % 192;
      int ci = v / 192;
      xs[ci][col] = x[((size_t)((b * kCin + cb + ci) * kH + 2 * y)) * kW + 2 * col];
    }
    __syncthreads();
#pragma unroll 4
    for (int ci = 0; ci < 16; ++ci) {
      float xv[3];
#pragma unroll
      for (int p = 0; p < 3; ++p) xv[p] = xs[ci][tx + 64 * p];
      const float* __restrict__ wp = dswT + (cb + ci) * kCout + ty * 16;
      float wv[16];
#pragma unroll
      for (int q = 0; q < 16; ++q) wv[q] = wp[q];
#pragma unroll
      for (int q = 0; q < 16; ++q)
#pragma unroll
        for (int p = 0; p < 3; ++p) acc[q][p] += xv[p] * wv[q];
    }
  }
#pragma unroll
  for (int q = 0; q < 16; ++q) {
    int ch = ty * 16 + q;
    float bt = beta[ch];
    int s = inv2[ch];
#pragma unroll
    for (int p = 0; p < 3; ++p) {
      float v = acc[q][p] + bt;
      if (s >= 0) v += o4[s][tx + 64 * p];
      v = v > 0.f ? v : 0.2f * v;
      out6[((size_t)(b * kCout + ch) * kHo + y) * kWo + tx + 64 * p] = v;
    }
  }
}

// ---------------------------------------------------------------------------
extern "C" void kernel_launch(void* const* d_in, const int* in_sizes, int n_in,
                              void* d_out, int out_size, void* d_ws, size_t ws_size,
                              hipStream_t stream) {
  (void)in_sizes; (void)n_in; (void)out_size; (void)ws_size;
  const float* x   = (const float*)d_in[0];
  const float* emb = (const float*)d_in[1];
  const float* w1  = (const float*)d_in[2];
  const float* w2  = (const float*)d_in[3];
  const float* dsw = (const float*)d_in[4];
  const float* dsg = (const float*)d_in[5];
  const float* dsb = (const float*)d_in[6];
  const float* gw1 = (const float*)d_in[7];
  const float* gb1 = (const float*)d_in[8];
  const float* gw2 = (const float*)d_in[9];
  const float* gb2 = (const float*)d_in[10];

  float* out6  = (float*)d_out;
  float* g_out = out6 + kOut6N;  // g1 [8][128] then g2 [8][128]

  float* wsf      = (float*)d_ws;
  int* act_idx    = (int*)d_ws;           // [2][8][32]
  float* act_gate = wsf + 512;            // [2][8][32]
  float* w1c      = wsf + 1024;           // 8*64*9*32
  float* w2c      = wsf + 148480;         // 8*32*9*32
  float* dswT     = wsf + 222208;         // 64*128
  float* out2c    = wsf + 230400;         // 8*32*96*192
  float* out4c    = wsf + 4948992;        // 8*32*96*192

  moe_gates_kernel<<<dim3(kB, 2), 64, 0, stream>>>(emb, gw1, gb1, gw2, gb2,
                                                   g_out, act_idx, act_gate);
  moe_gather_kernel<<<dim3(896), 256, 0, stream>>>(w1, w2, dsw, dsg, act_idx,
                                                   w1c, w2c, dswT);
  moe_conv1_kernel<<<dim3(kHo, kB), 512, 0, stream>>>(x, w1c, act_gate, out2c);
  moe_conv2_kernel<<<dim3(kHo, kB), 512, 0, stream>>>(out2c, w2c, act_gate + 256, out4c);
  moe_final_kernel<<<dim3(kHo, kB), 512, 0, stream>>>(x, dswT, dsb, act_idx + 256,
                                                      out4c, out6);
}

// Round 7
// 449.960 us; speedup vs baseline: 1.7061x; 1.0479x over previous
//
#include <hip/hip_runtime.h>
#include <math.h>

// Problem constants
#define kB   8
#define kCin 64
#define kCout 128
#define kH   192
#define kW   384
#define kHo  96
#define kWo  192
#define kE   128
#define kK   32
#define kOut6N (kB * kCout * kHo * kWo)  // 18,874,368

// ---------------------------------------------------------------------------
// Kernel 1: gates. One block per (batch, gate). 64 threads = 1 wave.
// ---------------------------------------------------------------------------
__global__ void moe_gates_kernel(const float* __restrict__ emb,
                                 const float* __restrict__ gw1, const float* __restrict__ gb1,
                                 const float* __restrict__ gw2, const float* __restrict__ gb2,
                                 float* __restrict__ g_out,      // [2][8][128] at d_out tail
                                 int* __restrict__ act_idx,      // [2][8][32]
                                 float* __restrict__ act_gate) { // [2][8][32]
  const int b = blockIdx.x;
  const int g = blockIdx.y;
  const int lane = threadIdx.x;  // 0..63
  const float* __restrict__ w = g ? gw2 : gw1;
  const float* __restrict__ bias = g ? gb2 : gb1;

  float l0 = bias[lane];
  float l1 = bias[lane + 64];
  for (int e = 0; e < kE; ++e) {
    float ev = emb[b * kE + e];
    l0 += ev * w[e * kCout + lane];
    l1 += ev * w[e * kCout + lane + 64];
  }

  float selv = 0.f;
  int seli = 0;
  const float NEG = -__builtin_inff();
  for (int i = 0; i < kK; ++i) {
    float v;
    int idx;
    if (l1 > l0) { v = l1; idx = lane + 64; } else { v = l0; idx = lane; }
    // butterfly argmax across 64 lanes, tie -> lowest index (matches lax.top_k)
    for (int m = 1; m < 64; m <<= 1) {
      float ov = __shfl_xor(v, m);
      int oi = __shfl_xor(idx, m);
      if (ov > v || (ov == v && oi < idx)) { v = ov; idx = oi; }
    }
    if (lane == i) { selv = v; seli = idx; }
    if (idx == lane) l0 = NEG;
    else if (idx == lane + 64) l1 = NEG;
  }
  float m0 = __shfl(selv, 0);
  float ev = (lane < kK) ? expf(selv - m0) : 0.f;
  float s = ev;
  for (int m = 1; m < 64; m <<= 1) s += __shfl_xor(s, m);
  float gv = ev / s;

  __shared__ float gf[128];
  gf[lane] = 0.f;
  gf[lane + 64] = 0.f;
  __syncthreads();
  if (lane < kK) {
    act_idx[(g * kB + b) * kK + lane] = seli;
    act_gate[(g * kB + b) * kK + lane] = gv;
    gf[seli] = gv;
  }
  __syncthreads();
  g_out[(g * kB + b) * kCout + lane] = gf[lane];
  g_out[(g * kB + b) * kCout + lane + 64] = gf[lane + 64];
}

// ---------------------------------------------------------------------------
// Kernel 2: gather compact weights.
// ---------------------------------------------------------------------------
__global__ void moe_gather_kernel(const float* __restrict__ w1, const float* __restrict__ w2,
                                  const float* __restrict__ dsw, const float* __restrict__ gamma,
                                  const int* __restrict__ act_idx,
                                  float* __restrict__ w1c, float* __restrict__ w2c,
                                  float* __restrict__ dswT) {
  int idx = blockIdx.x * 256 + threadIdx.x;
  const int N1 = kB * kCin * 9 * kK;  // 147456
  const int N2 = kB * kK * 9 * kK;    // 73728
  const int N3 = kCin * kCout;        // 8192
  if (idx < N1) {
    int j = idx & 31;
    int t = idx >> 5;
    int r = t % 9;
    t /= 9;
    int ci = t % kCin;
    int b = t / kCin;
    int c = act_idx[b * kK + j];
    w1c[idx] = w1[(c * kCin + ci) * 9 + r];
  } else if ((idx -= N1) < N2) {
    int j = idx & 31;
    int t = idx >> 5;
    int r = t % 9;
    t /= 9;
    int i = t % kK;
    int b = t / kK;
    int co = act_idx[256 + b * kK + j];
    int cin = act_idx[b * kK + i];
    w2c[idx] = w2[(co * kCout + cin) * 9 + r];
  } else if ((idx -= N2) < N3) {
    int c = idx & 127;
    int ci = idx >> 7;
    dswT[idx] = dsw[c * kCin + ci] * gamma[c] / sqrtf(1.f + 1e-5f);
  }
}

// ---------------------------------------------------------------------------
// Kernel 3: conv1 (3x3 s2 p1), 32 active out-channels, *gate, leaky.
// Block (y,b), 512 threads = 8 waves. Wave ty: 4 out-ch; lane: 3 px (tx+64p).
// LDS parity-split: xsE[k]=x[2k], xsO[k]=x[2k-1]. Output col u needs
// O[u](kx=0), E[u](kx=1), O[u+1](kx=2) -> all lane-stride-1, conflict-free.
// ---------------------------------------------------------------------------
__global__ __launch_bounds__(512, 6) void moe_conv1_kernel(
    const float* __restrict__ x, const float* __restrict__ w1c,
    const float* __restrict__ act_gate, float* __restrict__ out2c) {
  const int y = blockIdx.x;
  const int b = blockIdx.y;
  const int tid = threadIdx.x;
  const int tx = tid & 63;
  const int ty = __builtin_amdgcn_readfirstlane(tid >> 6);  // 0..7

  __shared__ __align__(16) float xsE[8][3][200];  // E[k]=x[2k],   k=0..191 used
  __shared__ __align__(16) float xsO[8][3][200];  // O[k]=x[2k-1], k=0..192 used

  float acc[4][3];
#pragma unroll
  for (int c = 0; c < 4; ++c)
#pragma unroll
    for (int p = 0; p < 3; ++p) acc[c][p] = 0.f;

  for (int cb = 0; cb < kCin; cb += 8) {
    __syncthreads();
    // stage: 8ci*3r*96 float4 reads, de-interleaved into E/O; +24 O[0] zeros
    for (int v = tid; v < 2304 + 24; v += 512) {
      if (v < 2304) {
        int col4 = v % 96;  // global cols 4*col4 .. 4*col4+3
        int t = v / 96;
        int r = t % 3;
        int ci = t / 3;
        int grow = 2 * y - 1 + r;
        float4 val = make_float4(0.f, 0.f, 0.f, 0.f);
        if (grow >= 0)
          val = *(const float4*)&x[((size_t)((b * kCin + cb + ci) * kH + grow)) * kW + 4 * col4];
        // x[4c]=E[2c], x[4c+1]=O[2c+1], x[4c+2]=E[2c+1], x[4c+3]=O[2c+2]
        xsE[ci][r][2 * col4]     = val.x;
        xsE[ci][r][2 * col4 + 1] = val.z;
        xsO[ci][r][2 * col4 + 1] = val.y;
        xsO[ci][r][2 * col4 + 2] = val.w;
      } else {
        int e = v - 2304;  // 0..23: O[0] = x[-1] = 0 pad
        int r = e % 3;
        int ci = e / 3;
        xsO[ci][r][0] = 0.f;
      }
    }
    __syncthreads();
#pragma unroll 2
    for (int ci = 0; ci < 8; ++ci) {
      // xr[p][r][kx]: kx=0 -> O[u], kx=1 -> E[u], kx=2 -> O[u+1]; u = tx+64p
      float xr[3][3][3];
#pragma unroll
      for (int p = 0; p < 3; ++p)
#pragma unroll
        for (int r = 0; r < 3; ++r) {
          int u = tx + 64 * p;
          xr[p][r][0] = xsO[ci][r][u];
          xr[p][r][1] = xsE[ci][r][u];
          xr[p][r][2] = xsO[ci][r][u + 1];
        }
      const float* __restrict__ wp = w1c + (size_t)((b * kCin + cb + ci) * 9) * 32 + ty * 4;
#pragma unroll
      for (int ky = 0; ky < 3; ++ky)
#pragma unroll
        for (int kx = 0; kx < 3; ++kx) {
          const float4 wq = *(const float4*)&wp[(ky * 3 + kx) * 32];
          const float wv[4] = {wq.x, wq.y, wq.z, wq.w};
#pragma unroll
          for (int c = 0; c < 4; ++c)
#pragma unroll
            for (int p = 0; p < 3; ++p) acc[c][p] += xr[p][ky][kx] * wv[c];
        }
    }
  }
#pragma unroll
  for (int c = 0; c < 4; ++c) {
    int j = ty * 4 + c;
    float gv = act_gate[b * kK + j];
#pragma unroll
    for (int p = 0; p < 3; ++p) {
      float v = acc[c][p] * gv;
      v = v > 0.f ? v : 0.2f * v;
      out2c[((size_t)(b * kK + j) * kHo + y) * kWo + tx + 64 * p] = v;
    }
  }
}

// ---------------------------------------------------------------------------
// Kernel 4: conv2 (3x3 s1 p1) on compact 32-ch input -> 32 active out-ch.
// LDS reads already lane-stride-1 (conflict-free); float4 weight loads.
// ---------------------------------------------------------------------------
__global__ __launch_bounds__(512, 6) void moe_conv2_kernel(
    const float* __restrict__ out2c, const float* __restrict__ w2c,
    const float* __restrict__ act_gate2, float* __restrict__ out4c) {
  const int y = blockIdx.x;
  const int b = blockIdx.y;
  const int tid = threadIdx.x;
  const int tx = tid & 63;
  const int ty = __builtin_amdgcn_readfirstlane(tid >> 6);

  __shared__ __align__(16) float s2[8][3][200];  // col c <-> global col c-4

  float acc[4][3];
#pragma unroll
  for (int c = 0; c < 4; ++c)
#pragma unroll
    for (int p = 0; p < 3; ++p) acc[c][p] = 0.f;

  for (int cb = 0; cb < kK; cb += 8) {
    __syncthreads();
    // stage: 8ci*3r*48 float4 interior + 48 float4 zero edges
    for (int v = tid; v < 1152 + 48; v += 512) {
      if (v < 1152) {
        int col4 = v % 48;
        int t = v / 48;
        int r = t % 3;
        int ci = t / 3;
        int grow = y - 1 + r;
        float4 val = make_float4(0.f, 0.f, 0.f, 0.f);
        if (grow >= 0 && grow < kHo)
          val = *(const float4*)&out2c[((size_t)(b * kK + cb + ci) * kHo + grow) * kWo + 4 * col4];
        *(float4*)&s2[ci][r][4 + 4 * col4] = val;
      } else {
        int e = v - 1152;
        int side = e & 1;
        int t = e >> 1;
        int r = t % 3;
        int ci = t / 3;
        *(float4*)&s2[ci][r][side ? 196 : 0] = make_float4(0.f, 0.f, 0.f, 0.f);
      }
    }
    __syncthreads();
#pragma unroll 2
    for (int ci = 0; ci < 8; ++ci) {
      float xr[3][5];
#pragma unroll
      for (int r = 0; r < 3; ++r)
#pragma unroll
        for (int q = 0; q < 5; ++q) xr[r][q] = 0.f;
#pragma unroll
      for (int p = 0; p < 3; ++p)
#pragma unroll
        for (int r = 0; r < 3; ++r)
#pragma unroll
          for (int kx = 0; kx < 3; ++kx)
            xr[r][p + kx] = s2[ci][r][tx + 64 * p + kx + 3];  // note: overwrites agree
      const float* __restrict__ wp = w2c + (size_t)((b * kK + cb + ci) * 9) * 32 + ty * 4;
#pragma unroll
      for (int ky = 0; ky < 3; ++ky)
#pragma unroll
        for (int kx = 0; kx < 3; ++kx) {
          const float4 wq = *(const float4*)&wp[(ky * 3 + kx) * 32];
          const float wv[4] = {wq.x, wq.y, wq.z, wq.w};
#pragma unroll
          for (int c = 0; c < 4; ++c)
#pragma unroll
            for (int p = 0; p < 3; ++p) acc[c][p] += xr[ky][p + kx] * wv[c];
        }
    }
  }
#pragma unroll
  for (int c = 0; c < 4; ++c) {
    int j = ty * 4 + c;
    float gv = act_gate2[b * kK + j];
#pragma unroll
    for (int p = 0; p < 3; ++p) {
      float v = acc[c][p] * gv;
      v = v > 0.f ? v : 0.2f * v;
      out4c[((size_t)(b * kK + j) * kHo + y) * kWo + tx + 64 * p] = v;
    }
  }
}

// ---------------------------------------------------------------------------
// Kernel 5: fused downsample 1x1 s2 conv + BN + scatter-add out4 + leaky.
// ---------------------------------------------------------------------------
__global__ __launch_bounds__(512, 5) void moe_final_kernel(
    const float* __restrict__ x, const float* __restrict__ dswT,
    const float* __restrict__ beta, const int* __restrict__ act_idx2,
    const float* __restrict__ out4c, float* __restrict__ out6) {
  const int y = blockIdx.x;
  const int b = blockIdx.y;
  const int tid = threadIdx.x;
  const int tx = tid & 63;
  const int ty = __builtin_amdgcn_readfirstlane(tid >> 6);

  __shared__ __align__(16) float xs[16][192];
  __shared__ __align__(16) float o4[32][192];
  __shared__ int inv2[128];

  // stage o4 (float4), init inv2
  for (int v = tid; v < 1536; v += 512) {
    int col4 = v % 48;
    int s = v / 48;
    *(float4*)&o4[s][4 * col4] =
        *(const float4*)&out4c[((size_t)(b * kK + s) * kHo + y) * kWo + 4 * col4];
  }
  if (tid < 128) inv2[tid] = -1;
  __syncthreads();
  if (tid < kK) inv2[act_idx2[b * kK + tid]] = tid;

  float acc[16][3];
#pragma unroll
  for (int q = 0; q < 16; ++q)
#pragma unroll
    for (int p = 0; p < 3; ++p) acc[q][p] = 0.f;

  for (int cb = 0; cb < kCin; cb += 16) {
    __syncthreads();
    for (int v = tid; v < 16 * 192; v += 512) {
      int col = v % 192;
      int ci = v / 192;
      xs[ci][col] = x[((size_t)((b * kCin + ci + cb) * kH + 2 * y)) * kW + 2 * col];
    }
    __syncthreads();
#pragma unroll 4
    for (int ci = 0; ci < 16; ++ci) {
      float xv[3];
#pragma unroll
      for (int p = 0; p < 3; ++p) xv[p] = xs[ci][tx + 64 * p];
      const float* __restrict__ wp = dswT + (cb + ci) * kCout + ty * 16;
      float wv[16];
#pragma unroll
      for (int q = 0; q < 16; ++q) wv[q] = wp[q];
#pragma unroll
      for (int q = 0; q < 16; ++q)
#pragma unroll
        for (int p = 0; p < 3; ++p) acc[q][p] += xv[p] * wv[q];
    }
  }
#pragma unroll
  for (int q = 0; q < 16; ++q) {
    int ch = ty * 16 + q;
    float bt = beta[ch];
    int s = inv2[ch];
#pragma unroll
    for (int p = 0; p < 3; ++p) {
      float v = acc[q][p] + bt;
      if (s >= 0) v += o4[s][tx + 64 * p];
      v = v > 0.f ? v : 0.2f * v;
      out6[((size_t)(b * kCout + ch) * kHo + y) * kWo + tx + 64 * p] = v;
    }
  }
}

// ---------------------------------------------------------------------------
extern "C" void kernel_launch(void* const* d_in, const int* in_sizes, int n_in,
                              void* d_out, int out_size, void* d_ws, size_t ws_size,
                              hipStream_t stream) {
  (void)in_sizes; (void)n_in; (void)out_size; (void)ws_size;
  const float* x   = (const float*)d_in[0];
  const float* emb = (const float*)d_in[1];
  const float* w1  = (const float*)d_in[2];
  const float* w2  = (const float*)d_in[3];
  const float* dsw = (const float*)d_in[4];
  const float* dsg = (const float*)d_in[5];
  const float* dsb = (const float*)d_in[6];
  const float* gw1 = (const float*)d_in[7];
  const float* gb1 = (const float*)d_in[8];
  const float* gw2 = (const float*)d_in[9];
  const float* gb2 = (const float*)d_in[10];

  float* out6  = (float*)d_out;
  float* g_out = out6 + kOut6N;  // g1 [8][128] then g2 [8][128]

  float* wsf      = (float*)d_ws;
  int* act_idx    = (int*)d_ws;           // [2][8][32]
  float* act_gate = wsf + 512;            // [2][8][32]
  float* w1c      = wsf + 1024;           // 8*64*9*32
  float* w2c      = wsf + 148480;         // 8*32*9*32
  float* dswT     = wsf + 222208;         // 64*128
  float* out2c    = wsf + 230400;         // 8*32*96*192
  float* out4c    = wsf + 4948992;        // 8*32*96*192

  moe_gates_kernel<<<dim3(kB, 2), 64, 0, stream>>>(emb, gw1, gb1, gw2, gb2,
                                                   g_out, act_idx, act_gate);
  moe_gather_kernel<<<dim3(896), 256, 0, stream>>>(w1, w2, dsw, dsg, act_idx,
                                                   w1c, w2c, dswT);
  moe_conv1_kernel<<<dim3(kHo, kB), 512, 0, stream>>>(x, w1c, act_gate, out2c);
  moe_conv2_kernel<<<dim3(kHo, kB), 512, 0, stream>>>(out2c, w2c, act_gate + 256, out4c);
  moe_final_kernel<<<dim3(kHo, kB), 512, 0, stream>>>(x, dswT, dsb, act_idx + 256,
                                                      out4c, out6);
}